// Round 3
// baseline (34414.825 us; speedup 1.0000x reference)
//
#include <hip/hip_runtime.h>

// BiLSTM tagger, MI355X. Round 7: k_recurrent = barrier-free direct-poll dataflow.
// Round-6 post-mortem: VGPR_Count=60 proved the 16 float4 weights were NOT
// register-resident -- every inline asm in the loop had a "memory" clobber, which
// forbids LICM from hoisting the Whh loads (restrict can't override asm clobbers).
// 512 threads re-read 256B of weights from L2 every step. Fixes:
//   - NO "memory" clobbers in the main loop: stores/polls are volatile asm with
//     pure register operands; ordering via SSA data deps + volatile asm program
//     order. Weights hoist -> expect VGPR ~140.
//   - poll wave / LDS h relay / __syncthreads all removed: each lane (r,ke)
//     polls its own 16-unit tagged slice (8x dwordx4 = 32 VGPR). 2-slot safety:
//     a wave's tag-(s+1) store data-depends (via the 16-lane shfl reduce) on all
//     16 lanes matching tag s, and the 16 slices cover all 256 units => every
//     store of tag s+1 happens-after every wave consumed tag s-1 data.
//   - pregates: 16-step register window spread across ke lanes (lane ke holds
//     step s0+ke's 4 gates); 4 shfls deliver to ke==0 at use; refill = 4 loads
//     per lane per 16 steps (vmcnt(0) drain hits at most once per window).
//   - probe-verified same-XCD L2 exchange (plain store + sc0 load) with LLC
//     (sc0 sc1) fallback, as round 6 (probe passed, either path is correct).
//
// Workspace (d_ws) ~92.5 MB (unchanged layout):
//   [0)          preC      256 KB
//   [262144)     whhTc     256 KB
//   [524288)     embeds    12 MB   [8192][384]
//   [13107200)   pregates  64 MB   [2][8192][1024]
//   [80216064)   hout      16 MB   [8192][512]  ([hf|hb])
//   [96993280)   hbuf      8 KB    [2][2][256] u64 tagged h (tag=step+1)
// Probe/verdict scratch: last 256 B of d_out (zeroed by k_prep, overwritten by
// k_output at the end).

#define S_LEN 8192
#define LC    16
#define DW    256
#define DC    64
#define HC    128
#define H2    256
#define NG    1024   // 4*H2
#define NTAG  64
#define CV    128

typedef unsigned long long u64;

__device__ __forceinline__ float sigmoid_f(float x){
  return __frcp_rn(1.0f + __expf(-x));
}
__device__ __forceinline__ float tanh_f(float x){
  float a = fabsf(x);
  float t = 1.0f - 2.0f * __frcp_rn(__expf(2.0f*a) + 1.0f);
  return copysignf(t, x);
}

// ---------------------------------------------------------------- k_prep
// Also zeroes hbuf (blk 1) and the probe scratch (blk 0): stale tags/magics
// from a previous launch would otherwise falsely match.
__global__ __launch_bounds__(512) void k_prep(
    const float* __restrict__ char_emb, const float* __restrict__ char_Wih,
    const float* __restrict__ char_Whh, const float* __restrict__ char_b,
    float* __restrict__ preC, float* __restrict__ whhTc,
    u64* __restrict__ hbufz, unsigned* __restrict__ scratchz)
{
  int blk = blockIdx.x, tid = threadIdx.x;
  if (blk == 0 && tid < 64) scratchz[tid] = 0u;
  if (blk == 1){ hbufz[tid] = 0ull; hbufz[tid + 512] = 0ull; }

  __shared__ float esh[DC];
  if (blk < CV){
    if (tid < DC) esh[tid] = char_emb[blk*DC + tid];
    __syncthreads();
    const float* wr = char_Wih + (size_t)tid*DC;
    float acc = char_b[tid];
#pragma unroll
    for (int d=0; d<DC; d+=4){
      float4 wv = *(const float4*)&wr[d];
      acc += wv.x*esh[d] + wv.y*esh[d+1] + wv.z*esh[d+2] + wv.w*esh[d+3];
    }
    preC[(size_t)blk*512 + tid] = acc;
  } else {
    int k = blk - CV;
    whhTc[(size_t)k*512 + tid] = char_Whh[(size_t)tid*HC + k];
  }
}

// ---------------------------------------------------------------- k_char_lstm
__global__ __launch_bounds__(256) void k_char_lstm(
    const int* __restrict__ charsets, const int* __restrict__ lengths,
    const float* __restrict__ preC, const float* __restrict__ whhTc,
    float* __restrict__ embeds)
{
  int blk = blockIdx.x, tid = threadIdx.x;
  int s0 = blk*16;
  __shared__ float h_sh[16][132];
  __shared__ float gsh[512][17];
  __shared__ int   ch_sh[16];

  for (int i = tid; i < 16*132; i += 256) (&h_sh[0][0])[i] = 0.0f;

  int uw  = tid & 15;
  int ujg = tid >> 4;
  float c[8];
#pragma unroll
  for (int u=0; u<8; u++) c[u] = 0.0f;
  int lw = lengths[s0 + uw];

  int g0 = tid, g1 = tid + 256;
  __syncthreads();

  for (int t=0; t<LC; t++){
    if (tid < 16) ch_sh[tid] = charsets[(size_t)(s0+tid)*LC + t];
    __syncthreads();                                        // (A)

    float acc0[16], acc1[16];
#pragma unroll
    for (int w=0; w<16; w++){
      int ch = ch_sh[w];
      acc0[w] = preC[(size_t)ch*512 + g0];
      acc1[w] = preC[(size_t)ch*512 + g1];
    }
    for (int k4=0; k4<HC; k4+=4){
      float w00 = whhTc[(size_t)(k4+0)*512 + g0];
      float w01 = whhTc[(size_t)(k4+1)*512 + g0];
      float w02 = whhTc[(size_t)(k4+2)*512 + g0];
      float w03 = whhTc[(size_t)(k4+3)*512 + g0];
      float w10 = whhTc[(size_t)(k4+0)*512 + g1];
      float w11 = whhTc[(size_t)(k4+1)*512 + g1];
      float w12 = whhTc[(size_t)(k4+2)*512 + g1];
      float w13 = whhTc[(size_t)(k4+3)*512 + g1];
#pragma unroll
      for (int w=0; w<16; w++){
        float4 h4 = *(const float4*)&h_sh[w][k4];
        acc0[w] += w00*h4.x + w01*h4.y + w02*h4.z + w03*h4.w;
        acc1[w] += w10*h4.x + w11*h4.y + w12*h4.z + w13*h4.w;
      }
    }
#pragma unroll
    for (int w=0; w<16; w++){ gsh[g0][w] = acc0[w]; gsh[g1][w] = acc1[w]; }
    __syncthreads();                                        // (G)

    float hnew[8];
#pragma unroll
    for (int u=0; u<8; u++){
      int j = ujg*8 + u;
      float gi = sigmoid_f(gsh[j][uw]);
      float gf = sigmoid_f(gsh[HC + j][uw]);
      float gg = tanh_f   (gsh[2*HC + j][uw]);
      float go = sigmoid_f(gsh[3*HC + j][uw]);
      c[u] = gf*c[u] + gi*gg;
      hnew[u] = go * tanh_f(c[u]);
    }
#pragma unroll
    for (int u=0; u<8; u+=4)
      *(float4*)&h_sh[uw][ujg*8 + u] = make_float4(hnew[u],hnew[u+1],hnew[u+2],hnew[u+3]);
    if (t == lw-1){
#pragma unroll
      for (int u=0; u<8; u+=4)
        *(float4*)&embeds[(size_t)(s0+uw)*384 + ujg*8 + u]
            = make_float4(hnew[u],hnew[u+1],hnew[u+2],hnew[u+3]);
    }
  }
}

// ---------------------------------------------------------------- k_gather
__global__ __launch_bounds__(256) void k_gather(
    const int* __restrict__ sentence, const float* __restrict__ word_emb,
    float* __restrict__ embeds)
{
  int blk = blockIdx.x, tid = threadIdx.x;
  int s = blk*8 + (tid >> 5);
  int lane = tid & 31;
  int idx = sentence[s];
  const float4* src = (const float4*)(word_emb + (size_t)idx*DW);
  float4* dst = (float4*)(embeds + (size_t)s*384 + 128);
  dst[lane]      = src[lane];
  dst[lane + 32] = src[lane + 32];
}

// ---------------------------------------------------------------- k_pregate
// Output layout: pregates[dir][t][n], n = gate-major (PyTorch i,f,g,o blocks of 256)
__global__ __launch_bounds__(256) void k_pregate(
    const float* __restrict__ embeds,
    const float* __restrict__ Wih_fw, const float* __restrict__ b_fw,
    const float* __restrict__ Wih_bw, const float* __restrict__ b_bw,
    float* __restrict__ pregates)
{
  int dir = blockIdx.z;
  const float* W    = dir ? Wih_bw : Wih_fw;
  const float* bias = dir ? b_bw   : b_fw;
  int t0 = blockIdx.x*64, n0 = blockIdx.y*64;
  __shared__ float a_sh[16][68];
  __shared__ float b_sh[16][68];
  int tid = threadIdx.x;
  int li = tid & 63, kq = tid >> 6;
  int ti = tid >> 4, tj = tid & 15;
  float acc[4][4];
#pragma unroll
  for (int ii=0; ii<4; ii++)
#pragma unroll
    for (int jj=0; jj<4; jj++) acc[ii][jj] = 0.0f;

  for (int k0=0; k0<384; k0+=16){
    float4 av = *(const float4*)&embeds[(size_t)(t0+li)*384 + k0 + kq*4];
    float4 bv = *(const float4*)&W     [(size_t)(n0+li)*384 + k0 + kq*4];
    __syncthreads();
    a_sh[kq*4+0][li]=av.x; a_sh[kq*4+1][li]=av.y; a_sh[kq*4+2][li]=av.z; a_sh[kq*4+3][li]=av.w;
    b_sh[kq*4+0][li]=bv.x; b_sh[kq*4+1][li]=bv.y; b_sh[kq*4+2][li]=bv.z; b_sh[kq*4+3][li]=bv.w;
    __syncthreads();
#pragma unroll
    for (int kk=0; kk<16; kk++){
      float4 a4 = *(const float4*)&a_sh[kk][ti*4];
      float4 b4 = *(const float4*)&b_sh[kk][tj*4];
      float aa[4] = {a4.x,a4.y,a4.z,a4.w};
      float bb[4] = {b4.x,b4.y,b4.z,b4.w};
#pragma unroll
      for (int ii=0; ii<4; ii++)
#pragma unroll
        for (int jj=0; jj<4; jj++) acc[ii][jj] += aa[ii]*bb[jj];
    }
  }
  float4 bias4 = *(const float4*)&bias[n0 + tj*4];
  float bb2[4] = {bias4.x,bias4.y,bias4.z,bias4.w};
#pragma unroll
  for (int ii=0; ii<4; ii++){
    float4 o = make_float4(acc[ii][0]+bb2[0], acc[ii][1]+bb2[1],
                           acc[ii][2]+bb2[2], acc[ii][3]+bb2[3]);
    *(float4*)&pregates[((size_t)dir*S_LEN + (t0+ti*4+ii))*NG + n0 + tj*4] = o;
  }
}

// ---------------------------------------------------------------- k_recurrent
// FAST (same-XCD, probe-verified): plain store (write-through L1 -> shared L2),
//   sc0 load (L1 bypass, reads the shared L2).
// LLC  (always-correct fallback): sc0 sc1 both ways = device coherence point.
// Probe helpers keep "memory" clobbers (outside the hot loop, cheap & safe).
__device__ __forceinline__ void st_plain_u32(unsigned* p, unsigned v){
  asm volatile("global_store_dword %0, %1, off" :: "v"(p), "v"(v) : "memory");
}
__device__ __forceinline__ unsigned ld_sc0_u32(const unsigned* p){
  unsigned r;
  asm volatile("global_load_dword %0, %1, off sc0\n\t"
               "s_waitcnt vmcnt(0)"
               : "=v"(r) : "v"(p) : "memory");
  return r;
}

// 8x dwordx4 poll of one lane's 16-unit tagged slice. NO memory clobber: the
// consumers read the asm OUTPUTS (SSA deps), volatile keeps it in the loop.
#define POLL8(BITS) \
  asm volatile( \
    "global_load_dwordx4 %0, %8, off " BITS "\n\t" \
    "global_load_dwordx4 %1, %8, off offset:16 " BITS "\n\t" \
    "global_load_dwordx4 %2, %8, off offset:32 " BITS "\n\t" \
    "global_load_dwordx4 %3, %8, off offset:48 " BITS "\n\t" \
    "global_load_dwordx4 %4, %8, off offset:64 " BITS "\n\t" \
    "global_load_dwordx4 %5, %8, off offset:80 " BITS "\n\t" \
    "global_load_dwordx4 %6, %8, off offset:96 " BITS "\n\t" \
    "global_load_dwordx4 %7, %8, off offset:112 " BITS "\n\t" \
    "s_waitcnt vmcnt(0)" \
    : "=&v"(r0),"=&v"(r1),"=&v"(r2),"=&v"(r3), \
      "=&v"(r4),"=&v"(r5),"=&v"(r6),"=&v"(r7) \
    : "v"(pp))

#define TAGBAD \
  ((__float_as_uint(r0.x)^tg)|(__float_as_uint(r0.z)^tg)| \
   (__float_as_uint(r1.x)^tg)|(__float_as_uint(r1.z)^tg)| \
   (__float_as_uint(r2.x)^tg)|(__float_as_uint(r2.z)^tg)| \
   (__float_as_uint(r3.x)^tg)|(__float_as_uint(r3.z)^tg)| \
   (__float_as_uint(r4.x)^tg)|(__float_as_uint(r4.z)^tg)| \
   (__float_as_uint(r5.x)^tg)|(__float_as_uint(r5.z)^tg)| \
   (__float_as_uint(r6.x)^tg)|(__float_as_uint(r6.z)^tg)| \
   (__float_as_uint(r7.x)^tg)|(__float_as_uint(r7.z)^tg))

// Thread (r=tid>>4, ke=tid&15); unit = slot*32+r. Holds 4 gate rows x 16-k
// slice as 16 named float4s (VGPR-resident: no memory clobbers in loop).
// h slice arrives via direct poll: float4 .x=tag,.y=h (units 2j / 2j+1).
// Pregate window: lane ke holds step (w*16+ke)'s 4 gates; shfl to ke==0.
template<bool LLC>
__device__ __forceinline__ void compute_loop(
    int dir, int unit, int ke, int lane,
    const float* __restrict__ Whh,
    const float* __restrict__ pgb,
    u64* __restrict__ hb,
    float* __restrict__ hout)
{
  const float* bp = Whh + (size_t)unit*H2 + ke*16;
  float4 wA0 = *(const float4*)(bp + 0*65536 +  0);
  float4 wA1 = *(const float4*)(bp + 0*65536 +  4);
  float4 wA2 = *(const float4*)(bp + 0*65536 +  8);
  float4 wA3 = *(const float4*)(bp + 0*65536 + 12);
  float4 wB0 = *(const float4*)(bp + 1*65536 +  0);
  float4 wB1 = *(const float4*)(bp + 1*65536 +  4);
  float4 wB2 = *(const float4*)(bp + 1*65536 +  8);
  float4 wB3 = *(const float4*)(bp + 1*65536 + 12);
  float4 wC0 = *(const float4*)(bp + 2*65536 +  0);
  float4 wC1 = *(const float4*)(bp + 2*65536 +  4);
  float4 wC2 = *(const float4*)(bp + 2*65536 +  8);
  float4 wC3 = *(const float4*)(bp + 2*65536 + 12);
  float4 wD0 = *(const float4*)(bp + 3*65536 +  0);
  float4 wD1 = *(const float4*)(bp + 3*65536 +  4);
  float4 wD2 = *(const float4*)(bp + 3*65536 +  8);
  float4 wD3 = *(const float4*)(bp + 3*65536 + 12);

  // pregate window regs: current window (steps w*16+ke) and next.
  float p0c,p1c,p2c,p3c, p0n,p1n,p2n,p3n;
  {
    int t0 = dir ? (S_LEN-1-ke) : ke;
    const float* pa = pgb + (size_t)t0*NG + unit;
    p0c=pa[0]; p1c=pa[256]; p2c=pa[512]; p3c=pa[768];
    int t1 = dir ? (S_LEN-17-ke) : (16+ke);
    const float* pb = pgb + (size_t)t1*NG + unit;
    p0n=pb[0]; p1n=pb[256]; p2n=pb[512]; p3n=pb[768];
  }

  float4 r0,r1,r2,r3,r4,r5,r6,r7;     // polled slice; h(0)=0
  r0=r1=r2=r3=r4=r5=r6=r7 = make_float4(0.f,0.f,0.f,0.f);
  float c = 0.0f;

  u64* slot0 = hb + (size_t)ke*16;    // poll bases (lane slice)
  u64* slot1 = hb + H2 + (size_t)ke*16;

  for (int s=0; s<S_LEN; ++s){
    if (s && !(s & 15)){              // window boundary: rotate + refill
      p0c=p0n; p1c=p1n; p2c=p2n; p3c=p3n;
      int tl = s + 16 + ke; if (tl > S_LEN-1) tl = S_LEN-1;
      int t  = dir ? (S_LEN-1-tl) : tl;
      const float* pa = pgb + (size_t)t*NG + unit;
      p0n=pa[0]; p1n=pa[256]; p2n=pa[512]; p3n=pa[768];
    }

    // gates = Whh_slice . h_slice  (h values are .y/.w of poll regs)
    float a0 = wA0.x*r0.y + wA0.y*r0.w + wA0.z*r1.y + wA0.w*r1.w
             + wA1.x*r2.y + wA1.y*r2.w + wA1.z*r3.y + wA1.w*r3.w
             + wA2.x*r4.y + wA2.y*r4.w + wA2.z*r5.y + wA2.w*r5.w
             + wA3.x*r6.y + wA3.y*r6.w + wA3.z*r7.y + wA3.w*r7.w;
    float a1 = wB0.x*r0.y + wB0.y*r0.w + wB0.z*r1.y + wB0.w*r1.w
             + wB1.x*r2.y + wB1.y*r2.w + wB1.z*r3.y + wB1.w*r3.w
             + wB2.x*r4.y + wB2.y*r4.w + wB2.z*r5.y + wB2.w*r5.w
             + wB3.x*r6.y + wB3.y*r6.w + wB3.z*r7.y + wB3.w*r7.w;
    float a2 = wC0.x*r0.y + wC0.y*r0.w + wC0.z*r1.y + wC0.w*r1.w
             + wC1.x*r2.y + wC1.y*r2.w + wC1.z*r3.y + wC1.w*r3.w
             + wC2.x*r4.y + wC2.y*r4.w + wC2.z*r5.y + wC2.w*r5.w
             + wC3.x*r6.y + wC3.y*r6.w + wC3.z*r7.y + wC3.w*r7.w;
    float a3 = wD0.x*r0.y + wD0.y*r0.w + wD0.z*r1.y + wD0.w*r1.w
             + wD1.x*r2.y + wD1.y*r2.w + wD1.z*r3.y + wD1.w*r3.w
             + wD2.x*r4.y + wD2.y*r4.w + wD2.z*r5.y + wD2.w*r5.w
             + wD3.x*r6.y + wD3.y*r6.w + wD3.z*r7.y + wD3.w*r7.w;

    a0 += __shfl_xor(a0,1); a1 += __shfl_xor(a1,1); a2 += __shfl_xor(a2,1); a3 += __shfl_xor(a3,1);
    a0 += __shfl_xor(a0,2); a1 += __shfl_xor(a1,2); a2 += __shfl_xor(a2,2); a3 += __shfl_xor(a3,2);
    a0 += __shfl_xor(a0,4); a1 += __shfl_xor(a1,4); a2 += __shfl_xor(a2,4); a3 += __shfl_xor(a3,4);
    a0 += __shfl_xor(a0,8); a1 += __shfl_xor(a1,8); a2 += __shfl_xor(a2,8); a3 += __shfl_xor(a3,8);

    // pregate for step s from lane ((lane&48)|(s&15)) of the window regs
    int src = (lane & 48) | (s & 15);
    float g0 = __shfl(p0c, src, 64);
    float g1 = __shfl(p1c, src, 64);
    float g2 = __shfl(p2c, src, 64);
    float g3 = __shfl(p3c, src, 64);

    if (ke == 0){
      a0 += g0; a1 += g1; a2 += g2; a3 += g3;
      float gi = sigmoid_f(a0), gf = sigmoid_f(a1), gg = tanh_f(a2), go = sigmoid_f(a3);
      c = gf*c + gi*gg;
      float hn = go * tanh_f(c);
      u64 pack = ((u64)__float_as_uint(hn) << 32) | (u64)(unsigned)(s+1);
      u64* hp = (((s+1)&1) ? (hb + H2) : hb) + unit;
      if constexpr (LLC)
        asm volatile("global_store_dwordx2 %0, %1, off sc0 sc1" :: "v"(hp), "v"(pack));
      else
        asm volatile("global_store_dwordx2 %0, %1, off" :: "v"(hp), "v"(pack));
      int t = dir ? (S_LEN-1-s) : s;
      hout[(size_t)t*512 + (size_t)dir*H2 + unit] = hn;
    }

    if (s+1 < S_LEN){
      const u64* pp = ((s+1)&1) ? slot1 : slot0;
      unsigned tg = (unsigned)(s+1);
      if constexpr (LLC) { POLL8("sc0 sc1"); } else { POLL8("sc0"); }
      unsigned bad = TAGBAD;
      while (bad){
        if constexpr (LLC) { POLL8("sc0 sc1"); } else { POLL8("sc0"); }
        bad = TAGBAD;
      }
    }
  }
}

// 64 blocks x 512; active: (b&7)<2 (heuristic: one XCD per direction under
// round-robin dispatch; the probe verifies, fallback is always-correct).
__global__ __launch_bounds__(512, 1) void k_recurrent(
    const float* __restrict__ Whh_fw, const float* __restrict__ Whh_bw,
    const float* __restrict__ pregates,
    u64* __restrict__ hbuf,
    float* __restrict__ hout,
    unsigned* __restrict__ scratch)
{
  int b = blockIdx.x;
  if ((b & 7) > 1) return;
  const int dir  = b & 7;          // 0 or 1
  const int slot = b >> 3;         // 0..7
  const int tid  = threadIdx.x;

  __shared__ int fast_sh;

  // ---- functional same-XCD probe (bounded; any failure -> LLC fallback).
  // Scratch zeroed by k_prep each launch: no stale magics, verdicts are ANDs
  // of identical data -> no mixed-path hangs.
  if (tid == 0){
    unsigned* probe = scratch;        // [16]
    unsigned* verd1 = scratch + 16;   // [16]
    unsigned* verd2 = scratch + 32;   // [16]
    st_plain_u32(&probe[dir*8 + slot], 0xA5C70000u | (unsigned)slot);
    unsigned have = 0;
    for (int it = 0; it < 400 && have != 0xFFu; ++it)
      for (int i = 0; i < 8; ++i)
        if (!((have >> i) & 1u) &&
            ld_sc0_u32(&probe[dir*8 + i]) == (0xA5C70000u | (unsigned)i))
          have |= 1u << i;
    unsigned ok = (have == 0xFFu) ? 1u : 0u;
    __hip_atomic_store(&verd1[dir*8 + slot], 0x5EED0000u | ok,
                       __ATOMIC_RELAXED, __HIP_MEMORY_SCOPE_AGENT);
    unsigned f1 = 1;
    for (int i = 0; i < 8; ++i){
      unsigned v;
      do v = __hip_atomic_load(&verd1[dir*8 + i], __ATOMIC_RELAXED, __HIP_MEMORY_SCOPE_AGENT);
      while ((v & 0xFFFF0000u) != 0x5EED0000u);
      f1 &= v & 1u;
    }
    unsigned f2 = 0;
    if (f1){   // f1 identical across blocks (AND of same data) -> no hang
      st_plain_u32(&probe[dir*8 + slot], 0x0DDB0000u | (unsigned)slot);
      have = 0;
      for (int it = 0; it < 400 && have != 0xFFu; ++it)
        for (int i = 0; i < 8; ++i)
          if (!((have >> i) & 1u) &&
              ld_sc0_u32(&probe[dir*8 + i]) == (0x0DDB0000u | (unsigned)i))
            have |= 1u << i;
      ok = (have == 0xFFu) ? 1u : 0u;
      __hip_atomic_store(&verd2[dir*8 + slot], 0x7EED0000u | ok,
                         __ATOMIC_RELAXED, __HIP_MEMORY_SCOPE_AGENT);
      f2 = 1;
      for (int i = 0; i < 8; ++i){
        unsigned v;
        do v = __hip_atomic_load(&verd2[dir*8 + i], __ATOMIC_RELAXED, __HIP_MEMORY_SCOPE_AGENT);
        while ((v & 0xFFFF0000u) != 0x7EED0000u);
        f2 &= v & 1u;
      }
    }
    fast_sh = (int)(f1 & f2);
  }
  __syncthreads();
  const bool fast = (fast_sh != 0);

  const float* Whh = dir ? Whh_bw : Whh_fw;
  const float* pgb = pregates + (size_t)dir * S_LEN * NG;
  u64* hb = hbuf + (size_t)dir * 2 * H2;

  int r = tid >> 4, ke = tid & 15, lane = tid & 63;
  int unit = slot*32 + r;
  if (fast) compute_loop<false>(dir, unit, ke, lane, Whh, pgb, hb, hout);
  else      compute_loop<true >(dir, unit, ke, lane, Whh, pgb, hb, hout);
}

// ---------------------------------------------------------------- k_output
__global__ __launch_bounds__(256) void k_output(
    const float* __restrict__ hout, const float* __restrict__ outW,
    const float* __restrict__ outb, float* __restrict__ out)
{
  __shared__ float wT[128][66];
  __shared__ float hsh[32][132];
  __shared__ float lsh[32][66];
  __shared__ float msh[32][2];
  int t0 = blockIdx.x*32, tid = threadIdx.x;
  int n  = tid & 63, tg = tid >> 6;
  int sl = tid >> 3, kg = tid & 7;
  int wn = tid & 63, wk = tid >> 6;
  float acc[8];
#pragma unroll
  for (int u=0; u<8; u++) acc[u] = 0.0f;

  for (int kc=0; kc<4; kc++){
    int k0 = kc*128;
    float4 wreg[8];
#pragma unroll
    for (int e=0; e<8; e++) wreg[e] = *(const float4*)&outW[(size_t)wn*512 + k0 + wk*32 + e*4];
    float4 hreg[4];
#pragma unroll
    for (int e=0; e<4; e++) hreg[e] = *(const float4*)&hout[(size_t)(t0+sl)*512 + k0 + kg*16 + e*4];
    __syncthreads();
#pragma unroll
    for (int e=0; e<8; e++){
      int kk = wk*32 + e*4;
      wT[kk+0][wn]=wreg[e].x; wT[kk+1][wn]=wreg[e].y; wT[kk+2][wn]=wreg[e].z; wT[kk+3][wn]=wreg[e].w;
    }
#pragma unroll
    for (int e=0; e<4; e++) *(float4*)&hsh[sl][kg*16 + e*4] = hreg[e];
    __syncthreads();
#pragma unroll
    for (int kk4=0; kk4<128; kk4+=4){
      float w0 = wT[kk4+0][n], w1 = wT[kk4+1][n], w2 = wT[kk4+2][n], w3 = wT[kk4+3][n];
#pragma unroll
      for (int u=0; u<8; u++){
        float4 h4 = *(const float4*)&hsh[tg*8+u][kk4];
        acc[u] += w0*h4.x + w1*h4.y + w2*h4.z + w3*h4.w;
      }
    }
  }
  float bn = outb[n];
#pragma unroll
  for (int u=0; u<8; u++) lsh[tg*8+u][n] = acc[u] + bn;
  __syncthreads();
  if (tid < 32){
    float M = -3.4e38f;
    for (int j=0; j<NTAG; j++) M = fmaxf(M, lsh[tid][j]);
    float ssum = 0.0f;
    for (int j=0; j<NTAG; j++) ssum += expf(lsh[tid][j] - M);
    msh[tid][0] = M; msh[tid][1] = logf(ssum);
  }
  __syncthreads();
#pragma unroll
  for (int u=0; u<8; u++){
    int tt = tg*8+u;
    out[(size_t)(t0+tt)*NTAG + n] = lsh[tt][n] - msh[tt][0] - msh[tt][1];
  }
}

// ---------------------------------------------------------------- launch
extern "C" void kernel_launch(void* const* d_in, const int* in_sizes, int n_in,
                              void* d_out, int out_size, void* d_ws, size_t ws_size,
                              hipStream_t stream)
{
  (void)in_sizes; (void)n_in; (void)out_size; (void)ws_size;
  const int*   sentence = (const int*)d_in[0];
  const int*   charsets = (const int*)d_in[1];
  const int*   char_len = (const int*)d_in[2];
  const float* word_emb = (const float*)d_in[3];
  const float* char_emb = (const float*)d_in[4];
  const float* char_Wih = (const float*)d_in[5];
  const float* char_Whh = (const float*)d_in[6];
  const float* char_b   = (const float*)d_in[7];
  const float* fw_Wih   = (const float*)d_in[8];
  const float* fw_Whh   = (const float*)d_in[9];
  const float* fw_b     = (const float*)d_in[10];
  const float* bw_Wih   = (const float*)d_in[11];
  const float* bw_Whh   = (const float*)d_in[12];
  const float* bw_b     = (const float*)d_in[13];
  const float* out_W    = (const float*)d_in[14];
  const float* out_b    = (const float*)d_in[15];
  float* out = (float*)d_out;

  char* ws = (char*)d_ws;
  float* preC     = (float*)(ws);
  float* whhTc    = (float*)(ws + 262144);
  float* embeds   = (float*)(ws + 524288);
  float* pregates = (float*)(ws + 13107200);
  float* houtb    = (float*)(ws + 80216064);
  u64*   hbuf     = (u64*)(ws + 96993280);
  // probe/verdict scratch: last 256 B of d_out (zeroed by k_prep, overwritten
  // by k_output later).
  unsigned* scratch = (unsigned*)((float*)d_out + (size_t)S_LEN*NTAG - 64);

  k_prep     <<<256,  512, 0, stream>>>(char_emb, char_Wih, char_Whh, char_b,
                                        preC, whhTc, hbuf, scratch);
  k_char_lstm<<<512,  256, 0, stream>>>(charsets, char_len, preC, whhTc, embeds);
  k_gather   <<<1024, 256, 0, stream>>>(sentence, word_emb, embeds);
  k_pregate  <<<dim3(128,16,2), 256, 0, stream>>>(embeds, fw_Wih, fw_b, bw_Wih, bw_b, pregates);
  k_recurrent<<<64,   512, 0, stream>>>(fw_Whh, bw_Whh, pregates, hbuf, houtb, scratch);
  k_output   <<<256,  256, 0, stream>>>(houtb, out_W, out_b, out);
}

// Round 7
// 14956.944 us; speedup vs baseline: 2.3009x; 2.3009x over previous
//
#include <hip/hip_runtime.h>

// BiLSTM tagger, MI355X. Round 11: r9/r10 deadlock fixed.
// r9/r10 died twice in the harness with the identical kernel -> GPU hang, not
// infra. Root cause: main loop used intra-wave `if(ke==0){store}else{spin}`.
// For divergent if/else the COMPILER picks which side is emitted first in the
// wave's single instruction stream; if the spin side is first, every wave in
// every block spins on tags whose stores sit BEHIND the spin in the same
// wave's stream -> circular wait across blocks -> hang.
// Fix: poll is UNCONDITIONAL (all 64 lanes). Producer lanes execute st_tag and
// then the spin; volatile asms have fixed per-thread program order and a wave
// executes one instruction stream, so every store is issued before any lane of
// that wave can block. Every thread polls exactly one of the 256 units (own
// units included, replacing the producer's direct LDS h write) -- divergent
// branch is gone entirely. Backstop: bounded spin (65536 iters ~3ms, far above
// any legitimate wait) + sticky dead flag: a true deadlock now finishes with
// an absmax failure + counters instead of killing the harness.
// Design (from r9):
//  1) Weights FORCED into VGPRs via scalar "+v" asm pin (float4 "+v" was r8's
//     backend error). r4/r6/r7 failed weight residency (VGPR 96/60/68).
//     Verify: VGPR>=170.
//  2) One barrier/step, no gacc/poll-wave relays: lane (u,ke) = 4 gate rows x
//     32k of unit m; shfl_xor reduce over 8 ke-lanes; ke==0 lane activates +
//     tagged-stores h; then ALL lanes poll one unit each into LDS.
//  3) Pregates in double-buffered LDS window (16 steps x 128 gates): refill =
//     2 dwordx4/thread per 16 steps, issued at window start, ds_written 14
//     steps later.
//  Probe-verified same-XCD L2 exchange (plain store + sc0 load) with LLC
//  (sc0 sc1) fallback (correct either way; probe passed in r6/r7).
//
// Workspace (d_ws) ~92.5 MB (unchanged layout):
//   [0)          preC      256 KB
//   [262144)     whhTc     256 KB
//   [524288)     embeds    12 MB   [8192][384]
//   [13107200)   pregates  64 MB   [2][8192][1024]
//   [80216064)   hout      16 MB   [8192][512]  ([hf|hb])
//   [96993280)   hbuf      8 KB    [2][2][256] u64 tagged h (tag=step+1)
// Probe/verdict scratch: last 256 B of d_out (zeroed by k_prep, overwritten by
// k_output at the end).

#define S_LEN 8192
#define LC    16
#define DW    256
#define DC    64
#define HC    128
#define H2    256
#define NG    1024   // 4*H2
#define NTAG  64
#define CV    128

typedef unsigned long long u64;

__device__ __forceinline__ float sigmoid_f(float x){
  return __frcp_rn(1.0f + __expf(-x));
}
__device__ __forceinline__ float tanh_f(float x){
  float a = fabsf(x);
  float t = 1.0f - 2.0f * __frcp_rn(__expf(2.0f*a) + 1.0f);
  return copysignf(t, x);
}

// ---------------------------------------------------------------- k_prep
// Also zeroes hbuf (blk 1) and the probe scratch (blk 0): stale tags/magics
// from a previous launch would otherwise falsely match.
__global__ __launch_bounds__(512) void k_prep(
    const float* __restrict__ char_emb, const float* __restrict__ char_Wih,
    const float* __restrict__ char_Whh, const float* __restrict__ char_b,
    float* __restrict__ preC, float* __restrict__ whhTc,
    u64* __restrict__ hbufz, unsigned* __restrict__ scratchz)
{
  int blk = blockIdx.x, tid = threadIdx.x;
  if (blk == 0 && tid < 64) scratchz[tid] = 0u;
  if (blk == 1){ hbufz[tid] = 0ull; hbufz[tid + 512] = 0ull; }

  __shared__ float esh[DC];
  if (blk < CV){
    if (tid < DC) esh[tid] = char_emb[blk*DC + tid];
    __syncthreads();
    const float* wr = char_Wih + (size_t)tid*DC;
    float acc = char_b[tid];
#pragma unroll
    for (int d=0; d<DC; d+=4){
      float4 wv = *(const float4*)&wr[d];
      acc += wv.x*esh[d] + wv.y*esh[d+1] + wv.z*esh[d+2] + wv.w*esh[d+3];
    }
    preC[(size_t)blk*512 + tid] = acc;
  } else {
    int k = blk - CV;
    whhTc[(size_t)k*512 + tid] = char_Whh[(size_t)tid*HC + k];
  }
}

// ---------------------------------------------------------------- k_char_lstm
__global__ __launch_bounds__(256) void k_char_lstm(
    const int* __restrict__ charsets, const int* __restrict__ lengths,
    const float* __restrict__ preC, const float* __restrict__ whhTc,
    float* __restrict__ embeds)
{
  int blk = blockIdx.x, tid = threadIdx.x;
  int s0 = blk*16;
  __shared__ float h_sh[16][132];
  __shared__ float gsh[512][17];
  __shared__ int   ch_sh[16];

  for (int i = tid; i < 16*132; i += 256) (&h_sh[0][0])[i] = 0.0f;

  int uw  = tid & 15;
  int ujg = tid >> 4;
  float c[8];
#pragma unroll
  for (int u=0; u<8; u++) c[u] = 0.0f;
  int lw = lengths[s0 + uw];

  int g0 = tid, g1 = tid + 256;
  __syncthreads();

  for (int t=0; t<LC; t++){
    if (tid < 16) ch_sh[tid] = charsets[(size_t)(s0+tid)*LC + t];
    __syncthreads();                                        // (A)

    float acc0[16], acc1[16];
#pragma unroll
    for (int w=0; w<16; w++){
      int ch = ch_sh[w];
      acc0[w] = preC[(size_t)ch*512 + g0];
      acc1[w] = preC[(size_t)ch*512 + g1];
    }
    for (int k4=0; k4<HC; k4+=4){
      float w00 = whhTc[(size_t)(k4+0)*512 + g0];
      float w01 = whhTc[(size_t)(k4+1)*512 + g0];
      float w02 = whhTc[(size_t)(k4+2)*512 + g0];
      float w03 = whhTc[(size_t)(k4+3)*512 + g0];
      float w10 = whhTc[(size_t)(k4+0)*512 + g1];
      float w11 = whhTc[(size_t)(k4+1)*512 + g1];
      float w12 = whhTc[(size_t)(k4+2)*512 + g1];
      float w13 = whhTc[(size_t)(k4+3)*512 + g1];
#pragma unroll
      for (int w=0; w<16; w++){
        float4 h4 = *(const float4*)&h_sh[w][k4];
        acc0[w] += w00*h4.x + w01*h4.y + w02*h4.z + w03*h4.w;
        acc1[w] += w10*h4.x + w11*h4.y + w12*h4.z + w13*h4.w;
      }
    }
#pragma unroll
    for (int w=0; w<16; w++){ gsh[g0][w] = acc0[w]; gsh[g1][w] = acc1[w]; }
    __syncthreads();                                        // (G)

    float hnew[8];
#pragma unroll
    for (int u=0; u<8; u++){
      int j = ujg*8 + u;
      float gi = sigmoid_f(gsh[j][uw]);
      float gf = sigmoid_f(gsh[HC + j][uw]);
      float gg = tanh_f   (gsh[2*HC + j][uw]);
      float go = sigmoid_f(gsh[3*HC + j][uw]);
      c[u] = gf*c[u] + gi*gg;
      hnew[u] = go * tanh_f(c[u]);
    }
#pragma unroll
    for (int u=0; u<8; u+=4)
      *(float4*)&h_sh[uw][ujg*8 + u] = make_float4(hnew[u],hnew[u+1],hnew[u+2],hnew[u+3]);
    if (t == lw-1){
#pragma unroll
      for (int u=0; u<8; u+=4)
        *(float4*)&embeds[(size_t)(s0+uw)*384 + ujg*8 + u]
            = make_float4(hnew[u],hnew[u+1],hnew[u+2],hnew[u+3]);
    }
  }
}

// ---------------------------------------------------------------- k_gather
__global__ __launch_bounds__(256) void k_gather(
    const int* __restrict__ sentence, const float* __restrict__ word_emb,
    float* __restrict__ embeds)
{
  int blk = blockIdx.x, tid = threadIdx.x;
  int s = blk*8 + (tid >> 5);
  int lane = tid & 31;
  int idx = sentence[s];
  const float4* src = (const float4*)(word_emb + (size_t)idx*DW);
  float4* dst = (float4*)(embeds + (size_t)s*384 + 128);
  dst[lane]      = src[lane];
  dst[lane + 32] = src[lane + 32];
}

// ---------------------------------------------------------------- k_pregate
// Output layout: pregates[dir][t][n], n = gate-major (PyTorch i,f,g,o blocks of 256)
__global__ __launch_bounds__(256) void k_pregate(
    const float* __restrict__ embeds,
    const float* __restrict__ Wih_fw, const float* __restrict__ b_fw,
    const float* __restrict__ Wih_bw, const float* __restrict__ b_bw,
    float* __restrict__ pregates)
{
  int dir = blockIdx.z;
  const float* W    = dir ? Wih_bw : Wih_fw;
  const float* bias = dir ? b_bw   : b_fw;
  int t0 = blockIdx.x*64, n0 = blockIdx.y*64;
  __shared__ float a_sh[16][68];
  __shared__ float b_sh[16][68];
  int tid = threadIdx.x;
  int li = tid & 63, kq = tid >> 6;
  int ti = tid >> 4, tj = tid & 15;
  float acc[4][4];
#pragma unroll
  for (int ii=0; ii<4; ii++)
#pragma unroll
    for (int jj=0; jj<4; jj++) acc[ii][jj] = 0.0f;

  for (int k0=0; k0<384; k0+=16){
    float4 av = *(const float4*)&embeds[(size_t)(t0+li)*384 + k0 + kq*4];
    float4 bv = *(const float4*)&W     [(size_t)(n0+li)*384 + k0 + kq*4];
    __syncthreads();
    a_sh[kq*4+0][li]=av.x; a_sh[kq*4+1][li]=av.y; a_sh[kq*4+2][li]=av.z; a_sh[kq*4+3][li]=av.w;
    b_sh[kq*4+0][li]=bv.x; b_sh[kq*4+1][li]=bv.y; b_sh[kq*4+2][li]=bv.z; b_sh[kq*4+3][li]=bv.w;
    __syncthreads();
#pragma unroll
    for (int kk=0; kk<16; kk++){
      float4 a4 = *(const float4*)&a_sh[kk][ti*4];
      float4 b4 = *(const float4*)&b_sh[kk][tj*4];
      float aa[4] = {a4.x,a4.y,a4.z,a4.w};
      float bb[4] = {b4.x,b4.y,b4.z,b4.w};
#pragma unroll
      for (int ii=0; ii<4; ii++)
#pragma unroll
        for (int jj=0; jj<4; jj++) acc[ii][jj] += aa[ii]*bb[jj];
    }
  }
  float4 bias4 = *(const float4*)&bias[n0 + tj*4];
  float bb2[4] = {bias4.x,bias4.y,bias4.z,bias4.w};
#pragma unroll
  for (int ii=0; ii<4; ii++){
    float4 o = make_float4(acc[ii][0]+bb2[0], acc[ii][1]+bb2[1],
                           acc[ii][2]+bb2[2], acc[ii][3]+bb2[3]);
    *(float4*)&pregates[((size_t)dir*S_LEN + (t0+ti*4+ii))*NG + n0 + tj*4] = o;
  }
}

// ---------------------------------------------------------------- k_recurrent
// FAST (same-XCD, probe-verified): plain store (write-through L1 -> shared L2),
//   sc0 load (L1 bypass, reads the shared L2).
// LLC  (always-correct fallback): sc0 sc1 both ways = device coherence point.
__device__ __forceinline__ void st_plain_u32(unsigned* p, unsigned v){
  asm volatile("global_store_dword %0, %1, off" :: "v"(p), "v"(v) : "memory");
}
__device__ __forceinline__ unsigned ld_sc0_u32(const unsigned* p){
  unsigned r;
  asm volatile("global_load_dword %0, %1, off sc0\n\t"
               "s_waitcnt vmcnt(0)"
               : "=v"(r) : "v"(p) : "memory");
  return r;
}
template<bool LLC>
__device__ __forceinline__ u64 ld_tag(const u64* p){
  u64 r;
  if constexpr (LLC)
    asm volatile("global_load_dwordx2 %0, %1, off sc0 sc1\n\ts_waitcnt vmcnt(0)"
                 : "=v"(r) : "v"(p));
  else
    asm volatile("global_load_dwordx2 %0, %1, off sc0\n\ts_waitcnt vmcnt(0)"
                 : "=v"(r) : "v"(p));
  return r;
}
template<bool LLC>
__device__ __forceinline__ void st_tag(u64* p, u64 v){
  if constexpr (LLC)
    asm volatile("global_store_dwordx2 %0, %1, off sc0 sc1" :: "v"(p), "v"(v));
  else
    asm volatile("global_store_dwordx2 %0, %1, off" :: "v"(p), "v"(v));
}

// Pin 16 consecutive scalar floats into VGPRs (empty asm, tied scalar operands
// are supported; 128-bit tuple operands are not -- r8's compile failure).
#define PIN16(P) asm volatile("" : \
  "+v"((P)[0]), "+v"((P)[1]), "+v"((P)[2]), "+v"((P)[3]), \
  "+v"((P)[4]), "+v"((P)[5]), "+v"((P)[6]), "+v"((P)[7]), \
  "+v"((P)[8]), "+v"((P)[9]), "+v"((P)[10]),"+v"((P)[11]), \
  "+v"((P)[12]),"+v"((P)[13]),"+v"((P)[14]),"+v"((P)[15]))

// h_sh layout: unit u at (u>>5)*36 + (u&31), double-buffered (+288 per parity).
// pg_sh layout: window buffer 2176 floats = 16 steps x 136 (128 gates + pad),
// gate value (q,m) of local step t at t*136 + q*32 + m.
template<bool LLC>
__device__ __forceinline__ void recurrent_run(
    int dir, int slot, int tid,
    const float* __restrict__ Whh, const float* __restrict__ pgb,
    u64* __restrict__ hb, float* __restrict__ hout,
    float* h_sh, float* pg_sh)
{
  const int u  = (tid>>3)&7, ke = tid&7, wv = tid>>6;
  const int m  = wv*8 + u;                 // local unit 0..31
  const int unit = slot*32 + m;
  // pregate cooperative refill indices
  const int t_local = tid>>4;              // 0..15
  const int n0 = (tid*8) & 127;
  const int pgcol = ((n0>>5)<<8) + slot*32 + (n0&31);
  // poll assignment: EVERY thread polls exactly one unit (all 256 covered)
  const int ru = (slot*32 + 32 + tid) & 255;
  const int rud = (ru>>5)*36 + (ru&31);

  // ---- weights: 4 gate rows x 32-k slice as 128 scalars, pinned in VGPRs --
  float wf[128];
  {
    const float* wb = Whh + (size_t)unit*H2 + ke*32;
#pragma unroll
    for (int q=0; q<4; q++)
#pragma unroll
      for (int j=0; j<8; j++){
        float4 v = *(const float4*)(wb + q*65536 + j*4);
        wf[q*32+j*4+0]=v.x; wf[q*32+j*4+1]=v.y; wf[q*32+j*4+2]=v.z; wf[q*32+j*4+3]=v.w;
      }
  }
  PIN16(wf);      PIN16(wf+16);  PIN16(wf+32);  PIN16(wf+48);
  PIN16(wf+64);   PIN16(wf+80);  PIN16(wf+96);  PIN16(wf+112);

  // ---- LDS init: h(0)=0, pregate windows 0 and 1 -------------------------
  for (int i=tid; i<576; i+=256) h_sh[i] = 0.0f;
#pragma unroll
  for (int wq=0; wq<2; ++wq){
    int ts = wq*16 + t_local;
    int tt = dir ? (S_LEN-1-ts) : ts;
    const float* pa = pgb + (size_t)tt*NG + pgcol;
    float4 a = *(const float4*)pa;
    float4 b = *(const float4*)(pa+4);
    float* pd = pg_sh + wq*2176 + t_local*136 + n0;
    *(float4*)pd = a; *(float4*)(pd+4) = b;
  }
  __syncthreads();

  float c = 0.0f;
  float4 pf0 = make_float4(0,0,0,0), pf1 = pf0;
  bool dead = false;   // bounded-spin backstop: deadlock -> finish with wrong
                       // data (absmax fail + counters) instead of a GPU hang.

  for (int s=0; s<S_LEN; ++s){
    const int buf1 = ((s&1)^1)*288;
    // matvec: 4 gate rows x 32 k from LDS (lane ke hits banks 4ke..4ke+3; same-ke
    // lanes broadcast -> conflict-free)
    const float* hr = h_sh + (s&1)*288 + ke*36;
    float a0=0.f, a1=0.f, a2=0.f, a3=0.f;
#pragma unroll
    for (int j=0; j<8; j++){
      float4 h4 = *(const float4*)(hr + j*4);
      a0 += wf[  0+j*4]*h4.x + wf[  1+j*4]*h4.y + wf[  2+j*4]*h4.z + wf[  3+j*4]*h4.w;
      a1 += wf[ 32+j*4]*h4.x + wf[ 33+j*4]*h4.y + wf[ 34+j*4]*h4.z + wf[ 35+j*4]*h4.w;
      a2 += wf[ 64+j*4]*h4.x + wf[ 65+j*4]*h4.y + wf[ 66+j*4]*h4.z + wf[ 67+j*4]*h4.w;
      a3 += wf[ 96+j*4]*h4.x + wf[ 97+j*4]*h4.y + wf[ 98+j*4]*h4.z + wf[ 99+j*4]*h4.w;
    }
    a0 += __shfl_xor(a0,1); a1 += __shfl_xor(a1,1); a2 += __shfl_xor(a2,1); a3 += __shfl_xor(a3,1);
    a0 += __shfl_xor(a0,2); a1 += __shfl_xor(a1,2); a2 += __shfl_xor(a2,2); a3 += __shfl_xor(a3,2);
    a0 += __shfl_xor(a0,4); a1 += __shfl_xor(a1,4); a2 += __shfl_xor(a2,4); a3 += __shfl_xor(a3,4);

    // producer lanes: pregate add, activations, tagged store (masked single-if;
    // NO else-branch -> the store is emitted before the poll in the wave's one
    // instruction stream, so every store issues before any lane can block)
    if (ke == 0){
      const float* pr = pg_sh + ((s>>4)&1)*2176 + (s&15)*136 + m;
      a0 += pr[0]; a1 += pr[32]; a2 += pr[64]; a3 += pr[96];
      float gi = sigmoid_f(a0), gf = sigmoid_f(a1), gg = tanh_f(a2), go = sigmoid_f(a3);
      c = gf*c + gi*gg;
      float hn = go * tanh_f(c);
      u64 pack = ((u64)__float_as_uint(hn) << 32) | (u64)(unsigned)(s+1);
      st_tag<LLC>(hb + (size_t)((s+1)&1)*H2 + unit, pack);
      int t = dir ? (S_LEN-1-s) : s;
      hout[(size_t)t*512 + (size_t)dir*H2 + unit] = hn;
    }

    // ALL lanes: poll one unit into the next h buffer (bounded spin).
    if (!dead){
      const u64* pp = hb + (size_t)((s+1)&1)*H2 + ru;
      unsigned tg = (unsigned)(s+1);
      u64 v = ld_tag<LLC>(pp);
      int it = 0;
      while ((unsigned)v != tg && ++it < 65536) v = ld_tag<LLC>(pp);
      dead = ((unsigned)v != tg);
      h_sh[buf1 + rud] = __uint_as_float((unsigned)(v >> 32));
    }

    // pregate window machinery (all threads)
    const int sw = s & 15;
    if (sw == 0){
      int ts = s + 16 + t_local; if (ts > S_LEN-1) ts = S_LEN-1;
      int tt = dir ? (S_LEN-1-ts) : ts;
      const float* pa = pgb + (size_t)tt*NG + pgcol;
      pf0 = *(const float4*)pa; pf1 = *(const float4*)(pa+4);
    } else if (sw == 14){
      float* pd = pg_sh + (((s>>4)+1)&1)*2176 + t_local*136 + n0;
      *(float4*)pd = pf0; *(float4*)(pd+4) = pf1;
    }
    __syncthreads();
  }
}

__global__ __launch_bounds__(256, 1) void k_recurrent(
    const float* __restrict__ Whh_fw, const float* __restrict__ Whh_bw,
    const float* __restrict__ pregates,
    u64* __restrict__ hbuf,
    float* __restrict__ hout,
    unsigned* __restrict__ scratch)
{
  int b = blockIdx.x;
  if ((b & 7) > 1) return;
  const int dir  = b & 7;          // 0 or 1
  const int slot = b >> 3;         // 0..7
  const int tid  = threadIdx.x;

  __shared__ float h_sh[2*288];
  __shared__ float pg_sh[2*2176];
  __shared__ int fast_sh;

  // ---- functional same-XCD probe (bounded; any failure -> LLC fallback).
  // Scratch zeroed by k_prep each launch: no stale magics; verdicts are ANDs
  // of identical data -> no mixed-path hangs. Ran fine in r6/r7.
  if (tid == 0){
    unsigned* probe = scratch;        // [16]
    unsigned* verd1 = scratch + 16;   // [16]
    unsigned* verd2 = scratch + 32;   // [16]
    st_plain_u32(&probe[dir*8 + slot], 0xA5C70000u | (unsigned)slot);
    unsigned have = 0;
    for (int it = 0; it < 400 && have != 0xFFu; ++it)
      for (int i = 0; i < 8; ++i)
        if (!((have >> i) & 1u) &&
            ld_sc0_u32(&probe[dir*8 + i]) == (0xA5C70000u | (unsigned)i))
          have |= 1u << i;
    unsigned ok = (have == 0xFFu) ? 1u : 0u;
    __hip_atomic_store(&verd1[dir*8 + slot], 0x5EED0000u | ok,
                       __ATOMIC_RELAXED, __HIP_MEMORY_SCOPE_AGENT);
    unsigned f1 = 1;
    for (int i = 0; i < 8; ++i){
      unsigned v;
      do v = __hip_atomic_load(&verd1[dir*8 + i], __ATOMIC_RELAXED, __HIP_MEMORY_SCOPE_AGENT);
      while ((v & 0xFFFF0000u) != 0x5EED0000u);
      f1 &= v & 1u;
    }
    unsigned f2 = 0;
    if (f1){   // f1 identical across blocks (AND of same data) -> no hang
      st_plain_u32(&probe[dir*8 + slot], 0x0DDB0000u | (unsigned)slot);
      have = 0;
      for (int it = 0; it < 400 && have != 0xFFu; ++it)
        for (int i = 0; i < 8; ++i)
          if (!((have >> i) & 1u) &&
              ld_sc0_u32(&probe[dir*8 + i]) == (0x0DDB0000u | (unsigned)i))
            have |= 1u << i;
      ok = (have == 0xFFu) ? 1u : 0u;
      __hip_atomic_store(&verd2[dir*8 + slot], 0x7EED0000u | ok,
                         __ATOMIC_RELAXED, __HIP_MEMORY_SCOPE_AGENT);
      f2 = 1;
      for (int i = 0; i < 8; ++i){
        unsigned v;
        do v = __hip_atomic_load(&verd2[dir*8 + i], __ATOMIC_RELAXED, __HIP_MEMORY_SCOPE_AGENT);
        while ((v & 0xFFFF0000u) != 0x7EED0000u);
        f2 &= v & 1u;
      }
    }
    fast_sh = (int)(f1 & f2);
  }
  __syncthreads();
  const bool fast = (fast_sh != 0);

  const float* Whh = dir ? Whh_bw : Whh_fw;
  const float* pgb = pregates + (size_t)dir * S_LEN * NG;
  u64* hb = hbuf + (size_t)dir * 2 * H2;

  if (fast) recurrent_run<false>(dir, slot, tid, Whh, pgb, hb, hout, h_sh, pg_sh);
  else      recurrent_run<true >(dir, slot, tid, Whh, pgb, hb, hout, h_sh, pg_sh);
}

// ---------------------------------------------------------------- k_output
__global__ __launch_bounds__(256) void k_output(
    const float* __restrict__ hout, const float* __restrict__ outW,
    const float* __restrict__ outb, float* __restrict__ out)
{
  __shared__ float wT[128][66];
  __shared__ float hsh[32][132];
  __shared__ float lsh[32][66];
  __shared__ float msh[32][2];
  int t0 = blockIdx.x*32, tid = threadIdx.x;
  int n  = tid & 63, tg = tid >> 6;
  int sl = tid >> 3, kg = tid & 7;
  int wn = tid & 63, wk = tid >> 6;
  float acc[8];
#pragma unroll
  for (int u=0; u<8; u++) acc[u] = 0.0f;

  for (int kc=0; kc<4; kc++){
    int k0 = kc*128;
    float4 wreg[8];
#pragma unroll
    for (int e=0; e<8; e++) wreg[e] = *(const float4*)&outW[(size_t)wn*512 + k0 + wk*32 + e*4];
    float4 hreg[4];
#pragma unroll
    for (int e=0; e<4; e++) hreg[e] = *(const float4*)&hout[(size_t)(t0+sl)*512 + k0 + kg*16 + e*4];
    __syncthreads();
#pragma unroll
    for (int e=0; e<8; e++){
      int kk = wk*32 + e*4;
      wT[kk+0][wn]=wreg[e].x; wT[kk+1][wn]=wreg[e].y; wT[kk+2][wn]=wreg[e].z; wT[kk+3][wn]=wreg[e].w;
    }
#pragma unroll
    for (int e=0; e<4; e++) *(float4*)&hsh[sl][kg*16 + e*4] = hreg[e];
    __syncthreads();
#pragma unroll
    for (int kk4=0; kk4<128; kk4+=4){
      float w0 = wT[kk4+0][n], w1 = wT[kk4+1][n], w2 = wT[kk4+2][n], w3 = wT[kk4+3][n];
#pragma unroll
      for (int u=0; u<8; u++){
        float4 h4 = *(const float4*)&hsh[tg*8+u][kk4];
        acc[u] += w0*h4.x + w1*h4.y + w2*h4.z + w3*h4.w;
      }
    }
  }
  float bn = outb[n];
#pragma unroll
  for (int u=0; u<8; u++) lsh[tg*8+u][n] = acc[u] + bn;
  __syncthreads();
  if (tid < 32){
    float M = -3.4e38f;
    for (int j=0; j<NTAG; j++) M = fmaxf(M, lsh[tid][j]);
    float ssum = 0.0f;
    for (int j=0; j<NTAG; j++) ssum += expf(lsh[tid][j] - M);
    msh[tid][0] = M; msh[tid][1] = logf(ssum);
  }
  __syncthreads();
#pragma unroll
  for (int u=0; u<8; u++){
    int tt = tg*8+u;
    out[(size_t)(t0+tt)*NTAG + n] = lsh[tt][n] - msh[tt][0] - msh[tt][1];
  }
}

// ---------------------------------------------------------------- launch
extern "C" void kernel_launch(void* const* d_in, const int* in_sizes, int n_in,
                              void* d_out, int out_size, void* d_ws, size_t ws_size,
                              hipStream_t stream)
{
  (void)in_sizes; (void)n_in; (void)out_size; (void)ws_size;
  const int*   sentence = (const int*)d_in[0];
  const int*   charsets = (const int*)d_in[1];
  const int*   char_len = (const int*)d_in[2];
  const float* word_emb = (const float*)d_in[3];
  const float* char_emb = (const float*)d_in[4];
  const float* char_Wih = (const float*)d_in[5];
  const float* char_Whh = (const float*)d_in[6];
  const float* char_b   = (const float*)d_in[7];
  const float* fw_Wih   = (const float*)d_in[8];
  const float* fw_Whh   = (const float*)d_in[9];
  const float* fw_b     = (const float*)d_in[10];
  const float* bw_Wih   = (const float*)d_in[11];
  const float* bw_Whh   = (const float*)d_in[12];
  const float* bw_b     = (const float*)d_in[13];
  const float* out_W    = (const float*)d_in[14];
  const float* out_b    = (const float*)d_in[15];
  float* out = (float*)d_out;

  char* ws = (char*)d_ws;
  float* preC     = (float*)(ws);
  float* whhTc    = (float*)(ws + 262144);
  float* embeds   = (float*)(ws + 524288);
  float* pregates = (float*)(ws + 13107200);
  float* houtb    = (float*)(ws + 80216064);
  u64*   hbuf     = (u64*)(ws + 96993280);
  // probe/verdict scratch: last 256 B of d_out (zeroed by k_prep, overwritten
  // by k_output later).
  unsigned* scratch = (unsigned*)((float*)d_out + (size_t)S_LEN*NTAG - 64);

  k_prep     <<<256,  512, 0, stream>>>(char_emb, char_Wih, char_Whh, char_b,
                                        preC, whhTc, hbuf, scratch);
  k_char_lstm<<<512,  256, 0, stream>>>(charsets, char_len, preC, whhTc, embeds);
  k_gather   <<<1024, 256, 0, stream>>>(sentence, word_emb, embeds);
  k_pregate  <<<dim3(128,16,2), 256, 0, stream>>>(embeds, fw_Wih, fw_b, bw_Wih, bw_b, pregates);
  k_recurrent<<<64,   256, 0, stream>>>(fw_Whh, bw_Whh, pregates, hbuf, houtb, scratch);
  k_output   <<<256,  256, 0, stream>>>(houtb, out_W, out_b, out);
}